// Round 11
// baseline (281.992 us; speedup 1.0000x reference)
//
#include <hip/hip_runtime.h>
#include <stdint.h>

typedef _Float16 f16;
typedef _Float16 half8 __attribute__((ext_vector_type(8)));
typedef _Float16 half4 __attribute__((ext_vector_type(4)));
typedef __fp16 fp16x2 __attribute__((ext_vector_type(2)));
typedef float f32x4 __attribute__((ext_vector_type(4)));
typedef float f32x16 __attribute__((ext_vector_type(16)));
typedef uint32_t u32x4 __attribute__((ext_vector_type(4)));

static constexpr int Bsz = 2, S = 2048, E = 2048, H = 16, D = 128;
static constexpr int M = Bsz * S;        // 4096
static constexpr int N_QKV = 3 * H * D;  // 6144
static constexpr int HD = H * D;         // 2048

__device__ __forceinline__ void gload_lds16(const void* gp, void* lp) {
  __builtin_amdgcn_global_load_lds(
      (const __attribute__((address_space(1))) uint32_t*)(uintptr_t)gp,
      (__attribute__((address_space(3))) uint32_t*)(uint32_t)(uintptr_t)lp,
      16, 0, 0);
}

__device__ __forceinline__ uint32_t pkrtz(float a, float b) {
  fp16x2 r = __builtin_amdgcn_cvt_pkrtz(a, b);
  return __builtin_bit_cast(uint32_t, r);
}

// ---------- f32 -> f16 cast ----------
__global__ void cast_f32_f16(const float* __restrict__ in, f16* __restrict__ out) {
  size_t i = (size_t)(blockIdx.x * 256 + threadIdx.x) * 8;
  float4 a = *(const float4*)&in[i];
  float4 b = *(const float4*)&in[i + 4];
  half8 h;
  h[0] = (f16)a.x; h[1] = (f16)a.y; h[2] = (f16)a.z; h[3] = (f16)a.w;
  h[4] = (f16)b.x; h[5] = (f16)b.y; h[6] = (f16)b.z; h[7] = (f16)b.w;
  *(half8*)&out[i] = h;
}

// ---------- transpose 2048x2048 f32 [k][n] -> f16 [n][k] ----------
__global__ void transpose_cast(const float* __restrict__ wq, const float* __restrict__ wk,
                               const float* __restrict__ wv, const float* __restrict__ wo,
                               f16* __restrict__ wt, f16* __restrict__ wot) {
  __shared__ float tile[32][33];
  int z = blockIdx.z;
  const float* src = (z == 0) ? wq : (z == 1) ? wk : (z == 2) ? wv : wo;
  f16* dst = (z == 3) ? wot : wt + (size_t)z * E * HD;
  int bx = blockIdx.x * 32, by = blockIdx.y * 32;
  int tx = threadIdx.x, ty = threadIdx.y;
#pragma unroll
  for (int r = 0; r < 4; ++r)
    tile[ty + r * 8][tx] = src[(size_t)(by + ty + r * 8) * 2048 + bx + tx];
  __syncthreads();
#pragma unroll
  for (int r = 0; r < 4; ++r)
    dst[(size_t)(bx + ty + r * 8) * 2048 + by + tx] = (f16)tile[tx][ty + r * 8];
}

// ---------- 8-phase QKV GEMM: A[4096][2048] x Bt[6144][2048] -> C[4096][6144] ----------
// BM=256 BN=192 BK=64; 512 thr (8 waves 2Mx4N); grid 512 = exactly 2 rounds.
// LDS 112KB: A[2buf][2kh][256][32] + B[2buf][192][64]. Stage tile t+2 per phase;
// counted vmcnt(7) at p2/p4; bank-free swizzles (A: (r>>2)&3, B: lc^(r&7)).
__global__ __launch_bounds__(512, 1) void gemm8(const f16* __restrict__ A,
                                                const f16* __restrict__ Bt,
                                                f16* __restrict__ C) {
  __shared__ f16 lds[57344];
  const int Kk = 2048;
  const int NT = 32;
  const int t = threadIdx.x, l = t & 63, wv = t >> 6;
  const int wm = wv >> 2, wn = wv & 3;
  const int lr = l & 15, g = l >> 4;
  const int bid = blockIdx.x;
  const int ii = bid >> 3;
  const int bm = (bid & 7) * 2 + (ii & 1);  // A-panels L2-resident per XCD
  const int bn = ii >> 1;                   // 0..31
  // A staging: 512 thr cover 256 rows x 2 half-chunks per gload
  const int arow = t >> 1, ah = t & 1;
  const int fa = (arow >> 2) & 3;
  const int ca0 = (ah ^ fa) * 8;
  const int ca1 = ((2 | ah) ^ fa) * 8;
  const f16* Abase = A + (size_t)(bm * 256 + arow) * Kk;
  // B staging: 3 gloads cover 192 rows x 64 k
  const int brl = t >> 3, bc = t & 7;
  const int cbx = (bc ^ (brl & 7)) * 8;
  const f16* Bs0 = Bt + (size_t)(bn * 192 + brl) * Kk + cbx;
  const f16* Bs1 = Bt + (size_t)(bn * 192 + 64 + brl) * Kk + cbx;
  const f16* Bs2 = Bt + (size_t)(bn * 192 + 128 + brl) * Kk + cbx;

#define ABUF(b_, kh_) ((b_) * 16384 + (kh_) * 8192)
#define BBUF(b_) (32768 + (b_) * 12288)
#define STAGE_A(T_, kh_)                                                     \
  do {                                                                       \
    int ko_ = (T_) * 64 + (kh_) * 32;                                        \
    int bb_ = (T_) & 1;                                                      \
    gload_lds16(Abase + ko_ + ca0, &lds[ABUF(bb_, kh_) + t * 8]);            \
    gload_lds16(Abase + ko_ + ca1, &lds[ABUF(bb_, kh_) + 4096 + t * 8]);     \
  } while (0)
#define STAGE_B(T_)                                                          \
  do {                                                                       \
    int ko_ = (T_) * 64;                                                     \
    int bb_ = (T_) & 1;                                                      \
    gload_lds16(Bs0 + ko_, &lds[BBUF(bb_) + t * 8]);                         \
    gload_lds16(Bs1 + ko_, &lds[BBUF(bb_) + 4096 + t * 8]);                  \
    gload_lds16(Bs2 + ko_, &lds[BBUF(bb_) + 8192 + t * 8]);                  \
  } while (0)
#define LDA(mq_, kh_)                                                        \
  _Pragma("unroll") for (int i2 = 0; i2 < 4; ++i2) {                         \
    int ra = wm * 128 + ((mq_)*4 + i2) * 16 + lr;                            \
    int s_ = g ^ ((ra >> 2) & 3);                                            \
    af[i2] = *(const half8*)&lds[ABUF(cb, kh_) + (s_ >> 1) * 4096 + ra * 16 + (s_ & 1) * 8]; \
  }
#define LDB(kh_)                                                             \
  _Pragma("unroll") for (int nj = 0; nj < 3; ++nj) {                         \
    int rb = wn * 48 + nj * 16 + lr;                                         \
    bf[nj] = *(const half8*)&lds[BBUF(cb) + rb * 64 + (((kh_)*4 + g) ^ (rb & 7)) * 8]; \
  }
#define MM(mq_)                                                              \
  __builtin_amdgcn_s_setprio(1);                                             \
  _Pragma("unroll") for (int i2 = 0; i2 < 4; ++i2)                           \
  _Pragma("unroll") for (int nj = 0; nj < 3; ++nj)                           \
      acc[(mq_)*4 + i2][nj] =                                                \
          __builtin_amdgcn_mfma_f32_16x16x32_f16(af[i2], bf[nj], acc[(mq_)*4 + i2][nj], 0, 0, 0); \
  __builtin_amdgcn_s_setprio(0);
#define BAR() __builtin_amdgcn_s_barrier()
#define VM7() asm volatile("s_waitcnt vmcnt(7)" ::: "memory")
#define VM0() asm volatile("s_waitcnt vmcnt(0)" ::: "memory")

  f32x4 acc[8][3] = {};
  // prologue: tile0 full (7 loads) + tile1 A-kh0,B (5 loads)
  STAGE_A(0, 0); STAGE_A(0, 1); STAGE_B(0);
  STAGE_A(1, 0); STAGE_B(1);
  asm volatile("s_waitcnt vmcnt(5)" ::: "memory");
  BAR();

  for (int T = 0; T < NT; ++T) {
    const int cb = T & 1;
    half8 af[4], bf[3];
    // p1: kh0 m0-3 | stage A-kh1(T+1)
    LDA(0, 0); LDB(0);
    if (T + 1 < NT) STAGE_A(T + 1, 1);
    BAR(); MM(0); BAR();
    // p2: kh0 m4-7 | vmcnt
    LDA(1, 0);
    if (T >= NT - 3) { VM0(); } else { VM7(); }
    BAR(); MM(1); BAR();
    // p3: kh1 m0-3 | stage A-kh0(T+2)
    LDA(0, 1); LDB(1);
    if (T + 2 < NT) STAGE_A(T + 2, 0);
    BAR(); MM(0); BAR();
    // p4: kh1 m4-7 | stage B(T+2) | vmcnt
    LDA(1, 1);
    if (T + 2 < NT) STAGE_B(T + 2);
    if (T >= NT - 3) { VM0(); } else { VM7(); }
    BAR(); MM(1); BAR();
  }

  const int crow = bm * 256 + wm * 128 + g * 4;
  const int ccol = bn * 192 + wn * 48 + lr;
#pragma unroll
  for (int mi = 0; mi < 8; ++mi)
#pragma unroll
    for (int nj = 0; nj < 3; ++nj)
#pragma unroll
      for (int r = 0; r < 4; ++r)
        C[(size_t)(crow + mi * 16 + r) * N_QKV + ccol + nj * 16] = (f16)acc[mi][nj][r];
#undef ABUF
#undef BBUF
#undef STAGE_A
#undef STAGE_B
#undef LDA
#undef LDB
#undef MM
#undef BAR
#undef VM7
#undef VM0
}

// ---------- RoPE + split qkv[M][6144] -> Q,K [B*H][S][D] ----------
__global__ void rope_split(const f16* __restrict__ qkv, const float* __restrict__ cosb,
                           const float* __restrict__ sinb, f16* __restrict__ Q,
                           f16* __restrict__ Ko) {
  int idx = blockIdx.x * 256 + threadIdx.x;
  int d4 = idx & 15;
  int h = (idx >> 4) & 15;
  int s = (idx >> 8) & 2047;
  int b = idx >> 19;
  int d = d4 * 4;
  size_t mrow = (size_t)(b * S + s) * N_QKV;
  const f16* q = &qkv[mrow + h * D];
  const f16* k = &qkv[mrow + HD + h * D];
  size_t ob = ((size_t)(b * H + h) * S + s) * D;
  float4 c1 = *(const float4*)&cosb[s * D + d];
  float4 c2 = *(const float4*)&cosb[s * D + 64 + d];
  float4 s1 = *(const float4*)&sinb[s * D + d];
  float4 s2 = *(const float4*)&sinb[s * D + 64 + d];
  float c1a[4] = {c1.x, c1.y, c1.z, c1.w}, c2a[4] = {c2.x, c2.y, c2.z, c2.w};
  float s1a[4] = {s1.x, s1.y, s1.z, s1.w}, s2a[4] = {s2.x, s2.y, s2.z, s2.w};
  half4 qlo = *(const half4*)&q[d], qhi = *(const half4*)&q[d + 64];
  half4 klo = *(const half4*)&k[d], khi = *(const half4*)&k[d + 64];
  half4 oql, oqh, okl, okh;
#pragma unroll
  for (int j = 0; j < 4; ++j) {
    float ql = (float)qlo[j], qh = (float)qhi[j];
    float kl = (float)klo[j], kh = (float)khi[j];
    oql[j] = (f16)(ql * c1a[j] - qh * s1a[j]);
    oqh[j] = (f16)(qh * c2a[j] + ql * s2a[j]);
    okl[j] = (f16)(kl * c1a[j] - kh * s1a[j]);
    okh[j] = (f16)(kh * c2a[j] + kl * s2a[j]);
  }
  *(half4*)&Q[ob + d] = oql;  *(half4*)&Q[ob + d + 64] = oqh;
  *(half4*)&Ko[ob + d] = okl; *(half4*)&Ko[ob + d + 64] = okh;
}

// ---------- V transpose: qkv V-part -> VtG [bh][d][s] ----------
__global__ void transpose_v(const f16* __restrict__ qkv, f16* __restrict__ VtG) {
  __shared__ f16 tl[64][136];
  int bid = blockIdx.x;
  int bh = bid >> 5, st = bid & 31;
  int b = bh >> 4, h = bh & 15;
  int t = threadIdx.x;
  int s0 = st * 64;
#pragma unroll
  for (int rnd = 0; rnd < 4; ++rnd) {
    int row = rnd * 16 + (t >> 4);
    int ch = t & 15;
    half8 v = *(const half8*)&qkv[(size_t)(b * S + s0 + row) * N_QKV + 2 * HD + h * D + ch * 8];
    *(half8*)&tl[row][ch * 8] = v;
  }
  __syncthreads();
#pragma unroll
  for (int rnd = 0; rnd < 4; ++rnd) {
    int d = rnd * 32 + (t >> 3);
    int ch = t & 7;
    half8 v;
#pragma unroll
    for (int j = 0; j < 8; ++j) v[j] = tl[ch * 8 + j][d];
    *(half8*)&VtG[((size_t)bh * D + d) * S + s0 + ch * 8] = v;
  }
}

// Staging of one 32-k section (out-proj GEMM).
#define STAGE4(PTR, BASE, KOFF, DST)                                       \
  gload_lds16(&PTR[BASE + (KOFF) + scol], &DST[t * 8]);                    \
  gload_lds16(&PTR[BASE + (size_t)64 * Kk + (KOFF) + scol], &DST[2048 + t * 8]);

// ---------- out-proj GEMM: 128x128 BK=64; bm L2-resident per XCD ----------
template <typename OutT>
__global__ __launch_bounds__(256, 4) void gemm_bt(const f16* __restrict__ A,
                                                  const f16* __restrict__ Bt,
                                                  OutT* __restrict__ C,
                                                  int Nn, int Kk) {
  __shared__ f16 As[8192];
  __shared__ f16 Bs[8192];
  const int t = threadIdx.x, l = t & 63;
  const int wm = (t >> 7) & 1, wn = (t >> 6) & 1;
  const int bid = blockIdx.x;
  const int bm = (bid & 7) * 4 + ((bid >> 3) & 3);
  const int bn = bid >> 5;
  const int lr = l & 15, g = l >> 4;
  const int srow = t >> 2;
  const int scol = (((t & 3) ^ (srow & 3)) * 8);
  const size_t abase = (size_t)(bm * 128 + srow) * Kk;
  const size_t bbase = (size_t)(bn * 128 + srow) * Kk;
  f32x4 acc[4][4] = {};
  for (int k0 = 0; k0 < Kk; k0 += 64) {
    __syncthreads();
    STAGE4(A, abase, k0, As);
    STAGE4(Bt, bbase, k0, Bs);
    STAGE4(A, abase, k0 + 32, (As + 4096));
    STAGE4(Bt, bbase, k0 + 32, (Bs + 4096));
    __syncthreads();
#pragma unroll
    for (int kh = 0; kh < 2; ++kh) {
      const int so = kh * 4096;
      half8 af[4], bf[4];
#pragma unroll
      for (int i = 0; i < 4; ++i) {
        int ra = wm * 64 + i * 16 + lr;
        int rb = wn * 64 + i * 16 + lr;
        af[i] = *(const half8*)&As[so + ra * 32 + ((g ^ (ra & 3)) * 8)];
        bf[i] = *(const half8*)&Bs[so + rb * 32 + ((g ^ (rb & 3)) * 8)];
      }
#pragma unroll
      for (int i = 0; i < 4; ++i)
#pragma unroll
        for (int j = 0; j < 4; ++j)
          acc[i][j] = __builtin_amdgcn_mfma_f32_16x16x32_f16(af[i], bf[j], acc[i][j], 0, 0, 0);
    }
  }
#pragma unroll
  for (int i = 0; i < 4; ++i)
#pragma unroll
    for (int j = 0; j < 4; ++j) {
      int row = bm * 128 + wm * 64 + i * 16 + g * 4;
      int col = bn * 128 + wn * 64 + j * 16 + lr;
#pragma unroll
      for (int r = 0; r < 4; ++r)
        C[(size_t)(row + r) * Nn + col] = (OutT)acc[i][j][r];
    }
}

// ---------- flash attention: 32x32x16, swapped operands, defer-max ----------
__device__ __forceinline__ void stage_kv(const f16* __restrict__ Kg, const f16* __restrict__ Vg,
                                         f16* KsB, f16* VsB, int t, int kv) {
#pragma unroll
  for (int rnd = 0; rnd < 4; ++rnd) {
    int row = rnd * 16 + (t >> 4);
    int c = t & 15;
    gload_lds16(&Kg[(size_t)(kv + row) * D + ((c ^ (row & 7)) * 8)], &KsB[rnd * 2048 + t * 8]);
  }
#pragma unroll
  for (int rnd = 0; rnd < 4; ++rnd) {
    int row = rnd * 32 + (t >> 3);
    int c = t & 7;
    gload_lds16(&Vg[(size_t)row * S + kv + ((c ^ (row & 7)) * 8)], &VsB[rnd * 2048 + t * 8]);
  }
}

__global__ __launch_bounds__(256, 2) void flash_attn2(const f16* __restrict__ Q,
                                                      const f16* __restrict__ K,
                                                      const f16* __restrict__ Vt,
                                                      f16* __restrict__ O) {
  __shared__ f16 lds[2][16384];
  const int t = threadIdx.x, l = t & 63, w = t >> 6;
  const int c = l & 31, hi = l >> 5;
  int bid = blockIdx.x;
  bid = (bid & 7) * 64 + (bid >> 3);
  const int bh = bid >> 4, qt = bid & 15;
  const size_t baseQ = (size_t)bh * S * D;
  const f16* Kg = K + baseQ;
  const f16* Vg = Vt + (size_t)bh * D * S;
  const int q0 = qt * 128 + w * 32;
  half8 qf[8];
#pragma unroll
  for (int dc = 0; dc < 8; ++dc)
    qf[dc] = *(const half8*)&Q[baseQ + (size_t)(q0 + c) * D + dc * 16 + hi * 8];
  f32x16 o[4] = {};
  float m = -3.0e38f, ssum = 0.f;

  stage_kv(Kg, Vg, &lds[0][0], &lds[0][8192], t, 0);
  __syncthreads();

  for (int it = 0; it < S / 64; ++it) {
    const int cur = it & 1;
    const f16* KsB = &lds[cur][0];
    const f16* VsB = &lds[cur][8192];
    if (it + 1 < S / 64) stage_kv(Kg, Vg, &lds[cur ^ 1][0], &lds[cur ^ 1][8192], t, (it + 1) * 64);

    f32x16 s0 = {}, s1 = {};
    __builtin_amdgcn_s_setprio(1);
#pragma unroll
    for (int dc = 0; dc < 8; ++dc) {
      const int r0 = c, r1 = 32 + c;
      half8 kf0 = *(const half8*)&KsB[r0 * 128 + (((2 * dc + hi) ^ (r0 & 7)) * 8)];
      half8 kf1 = *(const half8*)&KsB[r1 * 128 + (((2 * dc + hi) ^ (r1 & 7)) * 8)];
      s0 = __builtin_amdgcn_mfma_f32_32x32x16_f16(kf0, qf[dc], s0, 0, 0, 0);
      s1 = __builtin_amdgcn_mfma_f32_32x32x16_f16(kf1, qf[dc], s1, 0, 0, 0);
    }
    __builtin_amdgcn_s_setprio(0);

    float tm = s0[0];
#pragma unroll
    for (int r = 1; r < 16; ++r) tm = fmaxf(tm, s0[r]);
#pragma unroll
    for (int r = 0; r < 16; ++r) tm = fmaxf(tm, s1[r]);
    tm = fmaxf(tm, __shfl_xor(tm, 32));
    if (!__all(tm <= m + 8.f)) {
      float mn = fmaxf(m, tm);
      float corr = __expf(m - mn);
      m = mn;
      ssum *= corr;
#pragma unroll
      for (int dt = 0; dt < 4; ++dt)
#pragma unroll
        for (int r = 0; r < 16; ++r) o[dt][r] *= corr;
    }
    float ts = 0.f;
#pragma unroll
    for (int r = 0; r < 16; ++r) { s0[r] = __expf(s0[r] - m); ts += s0[r]; }
#pragma unroll
    for (int r = 0; r < 16; ++r) { s1[r] = __expf(s1[r] - m); ts += s1[r]; }
    ts += __shfl_xor(ts, 32);
    ssum += ts;

    half8 pf[4];
#pragma unroll
    for (int ks = 0; ks < 4; ++ks) {
      const int B0 = 2 * (ks & 1), B1 = B0 + 1;
      uint32_t X0, X1, Y0, Y1;
      if (ks < 2) {
        X0 = pkrtz(s0[4 * B0 + 0], s0[4 * B0 + 1]);
        X1 = pkrtz(s0[4 * B0 + 2], s0[4 * B0 + 3]);
        Y0 = pkrtz(s0[4 * B1 + 0], s0[4 * B1 + 1]);
        Y1 = pkrtz(s0[4 * B1 + 2], s0[4 * B1 + 3]);
      } else {
        X0 = pkrtz(s1[4 * B0 + 0], s1[4 * B0 + 1]);
        X1 = pkrtz(s1[4 * B0 + 2], s1[4 * B0 + 3]);
        Y0 = pkrtz(s1[4 * B1 + 0], s1[4 * B1 + 1]);
        Y1 = pkrtz(s1[4 * B1 + 2], s1[4 * B1 + 3]);
      }
      asm volatile("v_permlane32_swap_b32 %0, %1" : "+v"(X0), "+v"(Y0));
      asm volatile("v_permlane32_swap_b32 %0, %1" : "+v"(X1), "+v"(Y1));
      u32x4 pw; pw[0] = X0; pw[1] = X1; pw[2] = Y0; pw[3] = Y1;
      pf[ks] = __builtin_bit_cast(half8, pw);
    }

    __builtin_amdgcn_s_setprio(1);
#pragma unroll
    for (int dt = 0; dt < 4; ++dt) {
      const int row = dt * 32 + c;
#pragma unroll
      for (int ks = 0; ks < 4; ++ks) {
        half8 vf = *(const half8*)&VsB[row * 64 + (((2 * ks + hi) ^ (row & 7)) * 8)];
        o[dt] = __builtin_amdgcn_mfma_f32_32x32x16_f16(vf, pf[ks], o[dt], 0, 0, 0);
      }
    }
    __builtin_amdgcn_s_setprio(0);
    __syncthreads();
  }

  const float inv = 1.f / ssum;
  const int b = bh >> 4, h = bh & 15;
  const size_t orow = ((size_t)(b * S + q0 + c)) * HD + h * D;
#pragma unroll
  for (int dt = 0; dt < 4; ++dt)
#pragma unroll
    for (int b2 = 0; b2 < 4; ++b2) {
      half4 h4;
#pragma unroll
      for (int a = 0; a < 4; ++a) h4[a] = (f16)(o[dt][4 * b2 + a] * inv);
      *(half4*)&O[orow + dt * 32 + 8 * b2 + 4 * hi] = h4;
    }
}

extern "C" void kernel_launch(void* const* d_in, const int* in_sizes, int n_in,
                              void* d_out, int out_size, void* d_ws, size_t ws_size,
                              hipStream_t stream) {
  (void)in_sizes; (void)n_in; (void)out_size; (void)ws_size;
  const float* hs = (const float*)d_in[0];
  const float* cosb = (const float*)d_in[1];
  const float* sinb = (const float*)d_in[2];
  const float* wq = (const float*)d_in[3];
  const float* wk = (const float*)d_in[4];
  const float* wv = (const float*)d_in[5];
  const float* wo = (const float*)d_in[6];
  float* out = (float*)d_out;
  char* ws = (char*)d_ws;
  f16* hs16 = (f16*)(ws);                 // 0-16M; attn aliases after qkv consumed
  f16* attn = (f16*)(ws);
  f16* wt   = (f16*)(ws + (16u << 20));   // 24M  [6144][2048]
  f16* wot  = (f16*)(ws + (40u << 20));   // 8M   [2048][2048]
  f16* qkv  = (f16*)(ws + (48u << 20));   // 48M  [4096][6144]
  f16* Qb   = (f16*)(ws + (96u << 20));   // 16M  [32][2048][128]
  f16* Kb   = (f16*)(ws + (112u << 20));  // 16M
  f16* VtG  = (f16*)(ws + (128u << 20));  // 16M  [32][128][2048]

  cast_f32_f16<<<dim3(4096), dim3(256), 0, stream>>>(hs, hs16);
  transpose_cast<<<dim3(64, 64, 4), dim3(32, 8), 0, stream>>>(wq, wk, wv, wo, wt, wot);
  gemm8<<<dim3(512), dim3(512), 0, stream>>>(hs16, wt, qkv);
  rope_split<<<dim3(4096), dim3(256), 0, stream>>>(qkv, cosb, sinb, Qb, Kb);
  transpose_v<<<dim3(1024), dim3(256), 0, stream>>>(qkv, VtG);
  flash_attn2<<<dim3(512), dim3(256), 0, stream>>>(Qb, Kb, VtG, attn);
  gemm_bt<float><<<dim3(512), dim3(256), 0, stream>>>(attn, wot, out, E, HD);
}